// Round 5
// baseline (167.287 us; speedup 1.0000x reference)
//
#include <hip/hip_runtime.h>

#define N_NODES 100000
#define N_EDGES 1600000
#define D 64
#define BROWS 128              // rows per bucket (was 256): 782 sort blocks -> 3/CU balance
#define NBK 782                // ceil(100000/128)
#define BCAP 2368              // bucket capacity (mean 2048, sigma 45 -> z=7)
#define PBLK 512               // scatter blocks
#define TPB 512                // scatter threads per block
#define CHUNK ((N_EDGES + PBLK - 1) / PBLK)   // 3125 edges per block
#define CURSTRIDE 32           // pad cursors to one line each

__device__ __forceinline__ unsigned short f2b(float f) {
    unsigned u = __float_as_uint(f);
    u += 0x7FFF + ((u >> 16) & 1);            // round-to-nearest-even
    return (unsigned short)(u >> 16);
}

// ---- pass 0: cursors start at each bucket's base ----
__global__ void init_cursor_kernel(int* __restrict__ cursor) {
    int b = blockIdx.x * blockDim.x + threadIdx.x;
    if (b < NBK) cursor[b * CURSTRIDE] = b * BCAP;
}

// ---- pass 1: fused count+partition. LDS hist -> reserve runs -> write epack ----
// No LDS edge staging (chunk stays L2-hot for the 2nd read); small LDS -> high occupancy.
__global__ __launch_bounds__(TPB) void scatter_direct_kernel(const int* __restrict__ ei,
                                                             int* __restrict__ cursor,
                                                             int* __restrict__ epack) {
    __shared__ int h[NBK];
    __shared__ int lbase[NBK];
    __shared__ int lcur[NBK];
    int t = threadIdx.x;
    for (int i = t; i < NBK; i += TPB) h[i] = 0;
    __syncthreads();
    int s = blockIdx.x * CHUNK;
    int e = min(s + CHUNK, N_EDGES);
    for (int i = s + t; i < e; i += TPB) {
        int r = ei[i], c = ei[N_EDGES + i];
        if (r != c) atomicAdd(&h[r >> 7], 1);
    }
    __syncthreads();
    for (int i = t; i < NBK; i += TPB) {
        int hv = h[i];
        lbase[i] = hv ? atomicAdd(&cursor[i * CURSTRIDE], hv) : 0;  // reserve contiguous run
        lcur[i] = 0;
    }
    __syncthreads();
    for (int i = s + t; i < e; i += TPB) {   // chunk is L2-hot from pass A
        int r = ei[i], c = ei[N_EDGES + i];
        if (r != c) {
            int b = r >> 7;
            int p = lbase[b] + atomicAdd(&lcur[b], 1);
            epack[p] = ((r & 127) << 17) | c;
        }
    }
}

// ---- pass 2: per-bucket LDS counting sort (in place) + rowinfo + fused bf16 convert ----
// 128-row buckets: 782 blocks (3/CU, 1.33x imbalance vs 2x before), 9.5 KB ebuf.
__global__ __launch_bounds__(256) void csr_sort_convert_kernel(const int* __restrict__ cursor,
                                                               int* __restrict__ epack,
                                                               int2* __restrict__ rowinfo,
                                                               const float* __restrict__ x,
                                                               unsigned short* __restrict__ xs) {
    __shared__ int ebuf[BCAP];     // 9.5 KB staging of the bucket's edges
    __shared__ int h[BROWS];
    __shared__ int sc[BROWS];
    __shared__ int cur[BROWS];
    __shared__ float dv[BROWS];
    int b = blockIdx.x;
    int t = threadIdx.x;
    int base = b * BCAP;
    int n = min(cursor[b * CURSTRIDE] - base, BCAP);
    for (int i = t; i < n; i += 256) ebuf[i] = epack[base + i];
    if (t < BROWS) h[t] = 0;
    __syncthreads();
    for (int i = t; i < n; i += 256) atomicAdd(&h[ebuf[i] >> 17], 1);
    __syncthreads();
    int v = 0;
    if (t < BROWS) { v = h[t]; sc[t] = v; }
    __syncthreads();
    for (int off = 1; off < BROWS; off <<= 1) {    // inclusive scan over 128 counts
        int u = (t < BROWS && t >= off) ? sc[t - off] : 0;
        __syncthreads();
        if (t < BROWS) sc[t] += u;
        __syncthreads();
    }
    if (t < BROWS) {
        int excl = sc[t] - v;
        int row = b * BROWS + t;
        if (row < N_NODES) rowinfo[row] = make_int2(base + excl, v);
        dv[t] = rsqrtf((float)(1 + v));
        cur[t] = excl;
    }
    __syncthreads();
    for (int i = t; i < n; i += 256) {             // scatter LDS -> sorted, in place in epack
        int p = ebuf[i];
        int pos = atomicAdd(&cur[p >> 17], 1);
        epack[base + pos] = (p & 0x1FFFF) << 7;    // pre-scaled: byte offset of row in xs
    }
    // fused convert for this bucket's rows: xs = bf16(x * dinv)
    int nrows = min(BROWS, N_NODES - b * BROWS);
    const float4* x4 = (const float4*)x;
    ushort4* xs4 = (ushort4*)xs;
    for (int i = t; i < nrows * 16; i += 256) {    // 16 float4 per row
        int rl = i >> 4;
        float4 vv = x4[(size_t)(b * BROWS + rl) * 16 + (i & 15)];
        float dd = dv[rl];
        ushort4 o;
        o.x = f2b(vv.x * dd);
        o.y = f2b(vv.y * dd);
        o.z = f2b(vv.z * dd);
        o.w = f2b(vv.w * dd);
        xs4[(size_t)(b * BROWS + rl) * 16 + (i & 15)] = o;
    }
}

// ---- pass 3: gather. One wave per row; lane = (half, feature-pair); halves take
// interleaved (even/odd) edges -> 2 edges (2 lines) per wave load, half the shfl/addr work.
// ALL loops wave-uniform (tail clamps shfl source lane, predicates the add). ----
__global__ __launch_bounds__(256) void gather_kernel(const unsigned short* __restrict__ xs,
                                                     const int2* __restrict__ rowinfo,
                                                     const int* __restrict__ colidx,
                                                     float* __restrict__ out) {
    int t = blockIdx.x * blockDim.x + threadIdx.x;
    int r = t >> 6;
    int lane = t & 63;
    if (r >= N_NODES) return;                      // wave-uniform exit
    int lp = lane & 31;            // feature pair: feats 2lp, 2lp+1
    int hf = lane >> 5;            // which half: takes edges 2k+hf
    int lpo = lp << 2;             // byte offset of the pair within a row
    int2 ri = rowinfo[r];
    int start = ri.x;
    int end = start + ri.y;
    float dr = rsqrtf((float)(1 + ri.y));
    const char* xsb = (const char*)xs;
    float ax = 0.0f, ay = 0.0f;
    if (hf == 0) {                 // self-loop term (xs already carries dinv[r])
        unsigned v = *(const unsigned*)(xsb + (((size_t)r) << 7) + lpo);
        ax = __uint_as_float(v << 16);
        ay = __uint_as_float(v & 0xFFFF0000u);
    }
    for (int j = start; j < end; j += 64) {
        int idx = j + lane;
        int cj = (idx < end) ? colidx[idx] : 0;    // coalesced tile of pre-scaled cols
        int n = min(64, end - j);
        int k = 0;
        for (; 2 * (k + 8) <= n; k += 8) {         // uniform condition, all lanes active
            int s0 = __shfl(cj, 2 * k + hf);
            int s1 = __shfl(cj, 2 * k + 2 + hf);
            int s2 = __shfl(cj, 2 * k + 4 + hf);
            int s3 = __shfl(cj, 2 * k + 6 + hf);
            int s4 = __shfl(cj, 2 * k + 8 + hf);
            int s5 = __shfl(cj, 2 * k + 10 + hf);
            int s6 = __shfl(cj, 2 * k + 12 + hf);
            int s7 = __shfl(cj, 2 * k + 14 + hf);
            unsigned v0 = *(const unsigned*)(xsb + (unsigned)(s0 + lpo));  // 16 lines in flight
            unsigned v1 = *(const unsigned*)(xsb + (unsigned)(s1 + lpo));
            unsigned v2 = *(const unsigned*)(xsb + (unsigned)(s2 + lpo));
            unsigned v3 = *(const unsigned*)(xsb + (unsigned)(s3 + lpo));
            unsigned v4 = *(const unsigned*)(xsb + (unsigned)(s4 + lpo));
            unsigned v5 = *(const unsigned*)(xsb + (unsigned)(s5 + lpo));
            unsigned v6 = *(const unsigned*)(xsb + (unsigned)(s6 + lpo));
            unsigned v7 = *(const unsigned*)(xsb + (unsigned)(s7 + lpo));
            float a0 = __uint_as_float(v0 << 16), b0 = __uint_as_float(v0 & 0xFFFF0000u);
            float a1 = __uint_as_float(v1 << 16), b1 = __uint_as_float(v1 & 0xFFFF0000u);
            float a2 = __uint_as_float(v2 << 16), b2 = __uint_as_float(v2 & 0xFFFF0000u);
            float a3 = __uint_as_float(v3 << 16), b3 = __uint_as_float(v3 & 0xFFFF0000u);
            float a4 = __uint_as_float(v4 << 16), b4 = __uint_as_float(v4 & 0xFFFF0000u);
            float a5 = __uint_as_float(v5 << 16), b5 = __uint_as_float(v5 & 0xFFFF0000u);
            float a6 = __uint_as_float(v6 << 16), b6 = __uint_as_float(v6 & 0xFFFF0000u);
            float a7 = __uint_as_float(v7 << 16), b7 = __uint_as_float(v7 & 0xFFFF0000u);
            ax += ((a0 + a1) + (a2 + a3)) + ((a4 + a5) + (a6 + a7));
            ay += ((b0 + b1) + (b2 + b3)) + ((b4 + b5) + (b6 + b7));
        }
        for (; 2 * (k + 4) <= n; k += 4) {         // uniform condition
            int s0 = __shfl(cj, 2 * k + hf);
            int s1 = __shfl(cj, 2 * k + 2 + hf);
            int s2 = __shfl(cj, 2 * k + 4 + hf);
            int s3 = __shfl(cj, 2 * k + 6 + hf);
            unsigned v0 = *(const unsigned*)(xsb + (unsigned)(s0 + lpo));
            unsigned v1 = *(const unsigned*)(xsb + (unsigned)(s1 + lpo));
            unsigned v2 = *(const unsigned*)(xsb + (unsigned)(s2 + lpo));
            unsigned v3 = *(const unsigned*)(xsb + (unsigned)(s3 + lpo));
            float a0 = __uint_as_float(v0 << 16), b0 = __uint_as_float(v0 & 0xFFFF0000u);
            float a1 = __uint_as_float(v1 << 16), b1 = __uint_as_float(v1 & 0xFFFF0000u);
            float a2 = __uint_as_float(v2 << 16), b2 = __uint_as_float(v2 & 0xFFFF0000u);
            float a3 = __uint_as_float(v3 << 16), b3 = __uint_as_float(v3 & 0xFFFF0000u);
            ax += (a0 + a1) + (a2 + a3);
            ay += (b0 + b1) + (b2 + b3);
        }
        for (; 2 * k < n; k++) {                   // UNIFORM tail: all lanes run the shfl
            int src = 2 * k + hf;
            int s0 = __shfl(cj, (src < n) ? src : (n - 1));  // clamp: valid source lane
            unsigned v0 = *(const unsigned*)(xsb + (unsigned)(s0 + lpo));
            if (src < n) {                         // predicate the accumulate only
                ax += __uint_as_float(v0 << 16);
                ay += __uint_as_float(v0 & 0xFFFF0000u);
            }
        }
    }
    ax += __shfl_xor(ax, 32);                      // combine halves
    ay += __shfl_xor(ay, 32);
    if (hf == 0) {
        float2 o;
        o.x = dr * ax;
        o.y = dr * ay;
        ((float2*)out)[(size_t)r * 32 + lp] = o;   // 256B coalesced per row
    }
}

extern "C" void kernel_launch(void* const* d_in, const int* in_sizes, int n_in,
                              void* d_out, int out_size, void* d_ws, size_t ws_size,
                              hipStream_t stream) {
    const float* x = (const float*)d_in[0];
    const int* ei = (const int*)d_in[1];
    float* out = (float*)d_out;

    // workspace (~21.1 MB): cursor | rowinfo | epack | xs
    int* cursor = (int*)d_ws;                              // [NBK*CURSTRIDE] = 100 KB
    int2* rowinfo = (int2*)(cursor + NBK * CURSTRIDE);     // [N_NODES] (start, cnt)
    int* epack = (int*)(rowinfo + N_NODES);                // [NBK*BCAP], sorted in place
    unsigned short* xs = (unsigned short*)(epack + NBK * BCAP); // [N_NODES*D]

    init_cursor_kernel<<<(NBK + 255) / 256, 256, 0, stream>>>(cursor);
    scatter_direct_kernel<<<PBLK, TPB, 0, stream>>>(ei, cursor, epack);
    csr_sort_convert_kernel<<<NBK, 256, 0, stream>>>(cursor, epack, rowinfo, x, xs);
    gather_kernel<<<(N_NODES * D + 255) / 256, 256, 0, stream>>>(xs, rowinfo, epack, out);
}

// Round 6
// 153.458 us; speedup vs baseline: 1.0901x; 1.0901x over previous
//
#include <hip/hip_runtime.h>

#define N_NODES 100000
#define N_EDGES 1600000
#define D 64
#define NB 391                 // buckets of 256 rows
#define BCAP 4480              // bucket capacity (mean 4093, sigma 64 -> z=6; proven)
#define PBLK 256               // scatter blocks: chunk 6250 -> ~16-edge runs (64B bursts)
#define STPB 1024              // scatter threads: 16 waves/CU (was 8 -> 25% occupancy)
#define TPB 512                // sort threads per block
#define CHUNK ((N_EDGES + PBLK - 1) / PBLK)   // 6250 edges per block
#define CURSTRIDE 32           // pad cursors to one line each
#define CROWS 64               // convert rows per block (1563 balanced blocks)

__device__ __forceinline__ unsigned short f2b(float f) {
    unsigned u = __float_as_uint(f);
    u += 0x7FFF + ((u >> 16) & 1);            // round-to-nearest-even
    return (unsigned short)(u >> 16);
}

// ---- pass 0: cursors start at each bucket's base (workspace is POISONED, must init) ----
__global__ void init_cursor_kernel(int* __restrict__ cursor) {
    int b = blockIdx.x * blockDim.x + threadIdx.x;
    if (b < NB) cursor[b * CURSTRIDE] = b * BCAP;
}

// ---- pass 1: fused count+partition. LDS hist -> reserve runs -> write epack ----
// 1024 threads/block: 16 waves/CU for this latency-bound kernel. No LDS edge staging
// (2nd pass re-reads the chunk L2-hot).
__global__ __launch_bounds__(STPB) void scatter_direct_kernel(const int* __restrict__ ei,
                                                              int* __restrict__ cursor,
                                                              int* __restrict__ epack) {
    __shared__ int h[NB];
    __shared__ int lbase[NB];
    __shared__ int lcur[NB];
    int t = threadIdx.x;
    for (int i = t; i < NB; i += STPB) h[i] = 0;
    __syncthreads();
    int s = blockIdx.x * CHUNK;
    int e = min(s + CHUNK, N_EDGES);
    for (int i = s + t; i < e; i += STPB) {
        int r = ei[i], c = ei[N_EDGES + i];
        if (r != c) atomicAdd(&h[r >> 8], 1);
    }
    __syncthreads();
    for (int i = t; i < NB; i += STPB) {
        int hv = h[i];
        lbase[i] = hv ? atomicAdd(&cursor[i * CURSTRIDE], hv) : 0;  // reserve contiguous run
        lcur[i] = 0;
    }
    __syncthreads();
    for (int i = s + t; i < e; i += STPB) {  // chunk is L2-hot from pass A
        int r = ei[i], c = ei[N_EDGES + i];
        if (r != c) {
            int b = r >> 8;
            int p = lbase[b] + atomicAdd(&lcur[b], 1);
            epack[p] = ((r & 255) << 17) | c;   // ~16-edge runs pack lines in L2
        }
    }
}

// ---- pass 2: per-bucket LDS counting sort (in place, 512 thr). NO convert here:
// the 1.53-blocks/CU imbalance taxes everything in this kernel 2x, so it carries
// only the irreducible sort. Writes rowinfo + dinv for the convert/gather kernels. ----
__global__ __launch_bounds__(TPB) void csr_sort_kernel(const int* __restrict__ cursor,
                                                       int* __restrict__ epack,
                                                       int2* __restrict__ rowinfo,
                                                       float* __restrict__ dinv) {
    __shared__ int ebuf[BCAP];     // 17.9 KB staging of the bucket's edges
    __shared__ int h[256];
    __shared__ int sc[256];
    __shared__ int cur[256];
    int b = blockIdx.x;
    int t = threadIdx.x;
    int base = b * BCAP;
    int n = min(cursor[b * CURSTRIDE] - base, BCAP);
    // int4-vectorized staging (base is 16B-aligned: BCAP*4 = 17920 = 1120*16)
    const int4* ep4 = (const int4*)(epack + base);
    int n4 = n >> 2;
    for (int i = t; i < n4; i += TPB) ((int4*)ebuf)[i] = ep4[i];
    for (int i = (n4 << 2) + t; i < n; i += TPB) ebuf[i] = epack[base + i];
    if (t < 256) h[t] = 0;
    __syncthreads();
    for (int i = t; i < n; i += TPB) atomicAdd(&h[ebuf[i] >> 17], 1);
    __syncthreads();
    int v = 0;
    if (t < 256) { v = h[t]; sc[t] = v; }
    __syncthreads();
    for (int off = 1; off < 256; off <<= 1) {      // inclusive scan over 256 counts
        int u = (t < 256 && t >= off) ? sc[t - off] : 0;
        __syncthreads();
        if (t < 256) sc[t] += u;
        __syncthreads();
    }
    if (t < 256) {
        int excl = sc[t] - v;
        int row = b * 256 + t;
        if (row < N_NODES) {
            rowinfo[row] = make_int2(base + excl, v);
            dinv[row] = rsqrtf((float)(1 + v));
        }
        cur[t] = excl;
    }
    __syncthreads();
    for (int i = t; i < n; i += TPB) {             // scatter LDS -> sorted, in place in epack
        int p = ebuf[i];
        int pos = atomicAdd(&cur[p >> 17], 1);
        epack[base + pos] = (p & 0x1FFFF) << 7;    // pre-scaled: byte offset of row in xs
    }
}

// ---- pass 3: balanced streaming convert. xs = bf16(x * dinv). 64 rows/block. ----
__global__ __launch_bounds__(256) void convert_kernel(const float* __restrict__ x,
                                                      const float* __restrict__ dinv,
                                                      unsigned short* __restrict__ xs) {
    __shared__ float dv[CROWS];
    int b = blockIdx.x;
    int t = threadIdx.x;
    int r0 = b * CROWS;
    int nrows = min(CROWS, N_NODES - r0);
    if (t < nrows) dv[t] = dinv[r0 + t];
    __syncthreads();
    const float4* x4 = (const float4*)x;
    ushort4* xs4 = (ushort4*)xs;
    for (int i = t; i < nrows * 16; i += 256) {    // 16 float4 per row, 4 iters/thread
        int rl = i >> 4;
        float4 vv = x4[(size_t)(r0 + rl) * 16 + (i & 15)];
        float dd = dv[rl];
        ushort4 o;
        o.x = f2b(vv.x * dd);
        o.y = f2b(vv.y * dd);
        o.z = f2b(vv.z * dd);
        o.w = f2b(vv.w * dd);
        xs4[(size_t)(r0 + rl) * 16 + (i & 15)] = o;
    }
}

// ---- pass 4: gather (UNCHANGED from the passing round-4 kernel). One wave per row;
// lane = (half, feature-pair); halves take interleaved edges; wave-uniform tail. ----
__global__ __launch_bounds__(256) void gather_kernel(const unsigned short* __restrict__ xs,
                                                     const int2* __restrict__ rowinfo,
                                                     const int* __restrict__ colidx,
                                                     float* __restrict__ out) {
    int t = blockIdx.x * blockDim.x + threadIdx.x;
    int r = t >> 6;
    int lane = t & 63;
    if (r >= N_NODES) return;                      // wave-uniform exit
    int lp = lane & 31;            // feature pair: feats 2lp, 2lp+1
    int hf = lane >> 5;            // which half: takes edges 2k+hf
    int lpo = lp << 2;             // byte offset of the pair within a row
    int2 ri = rowinfo[r];
    int start = ri.x;
    int end = start + ri.y;
    float dr = rsqrtf((float)(1 + ri.y));
    const char* xsb = (const char*)xs;
    float ax = 0.0f, ay = 0.0f;
    if (hf == 0) {                 // self-loop term (xs already carries dinv[r])
        unsigned v = *(const unsigned*)(xsb + (((size_t)r) << 7) + lpo);
        ax = __uint_as_float(v << 16);
        ay = __uint_as_float(v & 0xFFFF0000u);
    }
    for (int j = start; j < end; j += 64) {
        int idx = j + lane;
        int cj = (idx < end) ? colidx[idx] : 0;    // coalesced tile of pre-scaled cols
        int n = min(64, end - j);
        int k = 0;
        for (; 2 * (k + 8) <= n; k += 8) {         // uniform condition, all lanes active
            int s0 = __shfl(cj, 2 * k + hf);
            int s1 = __shfl(cj, 2 * k + 2 + hf);
            int s2 = __shfl(cj, 2 * k + 4 + hf);
            int s3 = __shfl(cj, 2 * k + 6 + hf);
            int s4 = __shfl(cj, 2 * k + 8 + hf);
            int s5 = __shfl(cj, 2 * k + 10 + hf);
            int s6 = __shfl(cj, 2 * k + 12 + hf);
            int s7 = __shfl(cj, 2 * k + 14 + hf);
            unsigned v0 = *(const unsigned*)(xsb + (unsigned)(s0 + lpo));  // 16 lines in flight
            unsigned v1 = *(const unsigned*)(xsb + (unsigned)(s1 + lpo));
            unsigned v2 = *(const unsigned*)(xsb + (unsigned)(s2 + lpo));
            unsigned v3 = *(const unsigned*)(xsb + (unsigned)(s3 + lpo));
            unsigned v4 = *(const unsigned*)(xsb + (unsigned)(s4 + lpo));
            unsigned v5 = *(const unsigned*)(xsb + (unsigned)(s5 + lpo));
            unsigned v6 = *(const unsigned*)(xsb + (unsigned)(s6 + lpo));
            unsigned v7 = *(const unsigned*)(xsb + (unsigned)(s7 + lpo));
            float a0 = __uint_as_float(v0 << 16), b0 = __uint_as_float(v0 & 0xFFFF0000u);
            float a1 = __uint_as_float(v1 << 16), b1 = __uint_as_float(v1 & 0xFFFF0000u);
            float a2 = __uint_as_float(v2 << 16), b2 = __uint_as_float(v2 & 0xFFFF0000u);
            float a3 = __uint_as_float(v3 << 16), b3 = __uint_as_float(v3 & 0xFFFF0000u);
            float a4 = __uint_as_float(v4 << 16), b4 = __uint_as_float(v4 & 0xFFFF0000u);
            float a5 = __uint_as_float(v5 << 16), b5 = __uint_as_float(v5 & 0xFFFF0000u);
            float a6 = __uint_as_float(v6 << 16), b6 = __uint_as_float(v6 & 0xFFFF0000u);
            float a7 = __uint_as_float(v7 << 16), b7 = __uint_as_float(v7 & 0xFFFF0000u);
            ax += ((a0 + a1) + (a2 + a3)) + ((a4 + a5) + (a6 + a7));
            ay += ((b0 + b1) + (b2 + b3)) + ((b4 + b5) + (b6 + b7));
        }
        for (; 2 * (k + 4) <= n; k += 4) {         // uniform condition
            int s0 = __shfl(cj, 2 * k + hf);
            int s1 = __shfl(cj, 2 * k + 2 + hf);
            int s2 = __shfl(cj, 2 * k + 4 + hf);
            int s3 = __shfl(cj, 2 * k + 6 + hf);
            unsigned v0 = *(const unsigned*)(xsb + (unsigned)(s0 + lpo));
            unsigned v1 = *(const unsigned*)(xsb + (unsigned)(s1 + lpo));
            unsigned v2 = *(const unsigned*)(xsb + (unsigned)(s2 + lpo));
            unsigned v3 = *(const unsigned*)(xsb + (unsigned)(s3 + lpo));
            float a0 = __uint_as_float(v0 << 16), b0 = __uint_as_float(v0 & 0xFFFF0000u);
            float a1 = __uint_as_float(v1 << 16), b1 = __uint_as_float(v1 & 0xFFFF0000u);
            float a2 = __uint_as_float(v2 << 16), b2 = __uint_as_float(v2 & 0xFFFF0000u);
            float a3 = __uint_as_float(v3 << 16), b3 = __uint_as_float(v3 & 0xFFFF0000u);
            ax += (a0 + a1) + (a2 + a3);
            ay += (b0 + b1) + (b2 + b3);
        }
        for (; 2 * k < n; k++) {                   // UNIFORM tail: all lanes run the shfl
            int src = 2 * k + hf;
            int s0 = __shfl(cj, (src < n) ? src : (n - 1));  // clamp: valid source lane
            unsigned v0 = *(const unsigned*)(xsb + (unsigned)(s0 + lpo));
            if (src < n) {                         // predicate the accumulate only
                ax += __uint_as_float(v0 << 16);
                ay += __uint_as_float(v0 & 0xFFFF0000u);
            }
        }
    }
    ax += __shfl_xor(ax, 32);                      // combine halves
    ay += __shfl_xor(ay, 32);
    if (hf == 0) {
        float2 o;
        o.x = dr * ax;
        o.y = dr * ay;
        ((float2*)out)[(size_t)r * 32 + lp] = o;   // 256B coalesced per row
    }
}

extern "C" void kernel_launch(void* const* d_in, const int* in_sizes, int n_in,
                              void* d_out, int out_size, void* d_ws, size_t ws_size,
                              hipStream_t stream) {
    const float* x = (const float*)d_in[0];
    const int* ei = (const int*)d_in[1];
    float* out = (float*)d_out;

    // workspace (~21.2 MB): cursor | rowinfo | dinv | epack | xs
    int* cursor = (int*)d_ws;                              // [NB*CURSTRIDE] = 50 KB
    int2* rowinfo = (int2*)(cursor + NB * CURSTRIDE);      // [N_NODES] (start, cnt)
    float* dinv = (float*)(rowinfo + N_NODES);             // [N_NODES]
    int* epack = (int*)(dinv + N_NODES);                   // [NB*BCAP], sorted in place
    unsigned short* xs = (unsigned short*)(epack + NB * BCAP); // [N_NODES*D], 16B-aligned

    init_cursor_kernel<<<(NB + 255) / 256, 256, 0, stream>>>(cursor);
    scatter_direct_kernel<<<PBLK, STPB, 0, stream>>>(ei, cursor, epack);
    csr_sort_kernel<<<NB, TPB, 0, stream>>>(cursor, epack, rowinfo, dinv);
    convert_kernel<<<(N_NODES + CROWS - 1) / CROWS, 256, 0, stream>>>(x, dinv, xs);
    gather_kernel<<<(N_NODES * D + 255) / 256, 256, 0, stream>>>(xs, rowinfo, epack, out);
}